// Round 6
// baseline (184.973 us; speedup 1.0000x reference)
//
#include <hip/hip_runtime.h>

#define IMG_H 480
#define IMG_W 480
#define ATT_H 30
#define ATT_W 30
#define ATT_N (ATT_H * ATT_W)
#define PAD 48
#define NCH 3
#define NB 32
#define STRIPS 32           // 480 rows / 15 rows per strip
#define ROWS_PER_STRIP 15

#define FP4_PER_ROW (IMG_W / 4)              // 120
#define FP4_PER_CH  (IMG_H * FP4_PER_ROW)    // 57600
#define FP4_PER_IMG (NCH * FP4_PER_CH)       // 172800
#define UNROLL 5
#define CHUNKS_PER_BLOCK (256 * UNROLL)      // 1280
#define GRIDX (FP4_PER_IMG / CHUNKS_PER_BLOCK) // 135

// Kernel 1: per-strip mask bbox. Each block computes theta (0.5*max) itself
// (deterministic, identical across blocks) and writes its strip's raw bbox to
// a private slot — no global atomics, no init dependency on ws contents.
__global__ void __launch_bounds__(256) mask_kernel(const float* __restrict__ atten,
                                                   int* __restrict__ strip_box) {
    const int strip = blockIdx.x;
    const int b = blockIdx.y;
    const int tid = threadIdx.x;
    __shared__ float s_att[ATT_N];
    __shared__ float s_red[4];
    __shared__ int s_box[4];   // minr, maxr, minc, maxc

    const float* a = atten + (size_t)b * ATT_N;
    for (int i = tid; i < ATT_N; i += 256) s_att[i] = a[i];
    if (tid == 0) { s_box[0] = IMG_H; s_box[1] = -1; s_box[2] = IMG_W; s_box[3] = -1; }
    __syncthreads();

    // block max over the 900 attention values (order-independent => exact)
    float m = -1e30f;
    for (int i = tid; i < ATT_N; i += 256) m = fmaxf(m, s_att[i]);
    #pragma unroll
    for (int off = 32; off > 0; off >>= 1) m = fmaxf(m, __shfl_down(m, off, 64));
    if ((tid & 63) == 0) s_red[tid >> 6] = m;
    __syncthreads();
    const float theta = 0.5f * fmaxf(fmaxf(s_red[0], s_red[1]), fmaxf(s_red[2], s_red[3]));

    const int y_base = strip * ROWS_PER_STRIP;
    int minr = IMG_H, maxr = -1, minc = IMG_W, maxc = -1;
    for (int p = tid; p < ROWS_PER_STRIP * IMG_W; p += 256) {
        const int yy = p / IMG_W;
        const int y = y_base + yy;
        const int x = p - yy * IMG_W;
        // source coords: (i+0.5)*(30/480) - 0.5, clipped — scale is exactly 1/16
        float sy = (y + 0.5f) * 0.0625f - 0.5f;
        sy = fminf(fmaxf(sy, 0.0f), (float)(ATT_H - 1));
        const float fy0 = floorf(sy);
        const int r0 = (int)fy0;
        const int r1 = min(r0 + 1, ATT_H - 1);
        const float wr = sy - fy0;

        float sx = (x + 0.5f) * 0.0625f - 0.5f;
        sx = fminf(fmaxf(sx, 0.0f), (float)(ATT_W - 1));
        const float fx0 = floorf(sx);
        const int c0 = (int)fx0;
        const int c1 = min(c0 + 1, ATT_W - 1);
        const float wc = sx - fx0;

        // same op order as reference: row blend first, then column blend
        const float rb0 = s_att[r0 * ATT_W + c0] * (1.0f - wr) + s_att[r1 * ATT_W + c0] * wr;
        const float rb1 = s_att[r0 * ATT_W + c1] * (1.0f - wr) + s_att[r1 * ATT_W + c1] * wr;
        const float v = rb0 * (1.0f - wc) + rb1 * wc;
        if (v >= theta) {
            minr = min(minr, y); maxr = max(maxr, y);
            minc = min(minc, x); maxc = max(maxc, x);
        }
    }
    atomicMin(&s_box[0], minr); atomicMax(&s_box[1], maxr);
    atomicMin(&s_box[2], minc); atomicMax(&s_box[3], maxc);
    __syncthreads();
    if (tid == 0) {
        int* dst = strip_box + ((size_t)b * STRIPS + strip) * 4;
        dst[0] = s_box[0]; dst[1] = s_box[1]; dst[2] = s_box[2]; dst[3] = s_box[3];
    }
}

// Kernel 1.5: per-image prep. Reduce strip bboxes, precompute bilinear tables
// (bit-exact same expressions), and detect the DEGENERATE full-crop case:
// h0==0 && h1==H && w0==0 && w1==W  =>  scale==1 exactly => sy==y, sx==x,
// wr==wc==0 => the reference's patch equals base BITWISE (all other taps have
// exact 0.0 weights; only -0.0 -> +0.0 can differ, absdiff 0). Flag goes in
// rowtab[.].w so blend needs no extra load.
__global__ void __launch_bounds__(512) prep_kernel(const int* __restrict__ strip_box,
                                                   int4* __restrict__ rowtab,
                                                   int4* __restrict__ coltab) {
    const int b = blockIdx.x;
    const int tid = threadIdx.x;

    int minr = IMG_H, maxr = -1, minc = IMG_W, maxc = -1;
    const int* sb = strip_box + (size_t)b * STRIPS * 4;
    #pragma unroll
    for (int s = 0; s < STRIPS; ++s) {
        minr = min(minr, sb[s * 4 + 0]); maxr = max(maxr, sb[s * 4 + 1]);
        minc = min(minc, sb[s * 4 + 2]); maxc = max(maxc, sb[s * 4 + 3]);
    }
    const int h0 = max(minr - PAD, 0);
    const int h1 = min(maxr + PAD, IMG_H);
    const int w0 = max(minc - PAD, 0);
    const int w1 = min(maxc + PAD, IMG_W);
    const float cropH = (float)(h1 - h0);
    const float cropW = (float)(w1 - w0);
    const int full = (h0 == 0 && h1 == IMG_H && w0 == 0 && w1 == IMG_W) ? 1 : 0;

    if (tid < IMG_H) {
        // row entry (reference op order, identical expressions to old blend)
        float sy = (tid + 0.5f) * (cropH / (float)IMG_H) - 0.5f;
        sy = fminf(fmaxf(sy, 0.0f), cropH - 1.0f);
        const float fy0 = floorf(sy);
        const float fy1 = fminf(fy0 + 1.0f, cropH - 1.0f);
        const float wr = sy - fy0;
        rowtab[(size_t)b * IMG_H + tid] =
            make_int4(h0 + (int)fy0, h0 + (int)fy1, __float_as_int(wr), full);

        // col entry
        float sx = (tid + 0.5f) * (cropW / (float)IMG_W) - 0.5f;
        sx = fminf(fmaxf(sx, 0.0f), cropW - 1.0f);
        const float fx0 = floorf(sx);
        const float fx1 = fminf(fx0 + 1.0f, cropW - 1.0f);
        const float wc = sx - fx0;
        coltab[(size_t)b * IMG_W + tid] =
            make_int4(w0 + (int)fx0, w0 + (int)fx1, __float_as_int(wc), 0);
    }
}

// Kernel 2 — ROUND 6: m13-copy-shaped fast path. Round 5's fast path still
// carried per-16B-chunk scaffolding: integer decompose, a dependent rowtab
// load, and a per-chunk branch between the load and the store, with no unroll
// (grid-stride) so only ~1 load in flight per wave. This version: 2-D grid
// (blockIdx.y = image), flag read ONCE per block (uniform => s_cbranch), then
// the fast path is a 5x-unrolled sequence of independent float4 load/store
// pairs — instruction-for-instruction the 6.3 TB/s m13 copy probe. General
// path keeps round-5's exact per-chunk arithmetic (bit-exact, data-independent
// correctness). If this is STILL ~52us, the gap to 6.3 TB/s is environmental
// and the kernel is at the effective memory-system roofline.
__global__ void __launch_bounds__(256) blend_kernel(const float* __restrict__ images,
                                                    const int4* __restrict__ rowtab,
                                                    const int4* __restrict__ coltab,
                                                    float* __restrict__ out) {
    const int b = blockIdx.y;
    const int tid = threadIdx.x;
    const int cbase = blockIdx.x * CHUNKS_PER_BLOCK + tid;  // chunk index in image
    const size_t gbase = (size_t)b * FP4_PER_IMG;
    const int full = rowtab[(size_t)b * IMG_H].w;           // uniform => scalar branch

    if (full) {
        const float4* src = (const float4*)images + gbase;
        float4* dst = (float4*)out + gbase;
        #pragma unroll
        for (int u = 0; u < UNROLL; ++u) {
            const int c = cbase + u * 256;
            const float4 v = src[c];
            float4 r;
            r.x = v.x * 0.6f + v.x * 0.4f;
            r.y = v.y * 0.6f + v.y * 0.4f;
            r.z = v.z * 0.6f + v.z * 0.4f;
            r.w = v.w * 0.6f + v.w * 0.4f;
            dst[c] = r;
        }
    } else {
        // general path — exact round-5 expressions
        #pragma unroll
        for (int u = 0; u < UNROLL; ++u) {
            const int c = cbase + u * 256;
            const int ch   = c / FP4_PER_CH;
            const int rem2 = c - ch * FP4_PER_CH;
            const int y    = rem2 / FP4_PER_ROW;
            const int xq   = rem2 - y * FP4_PER_ROW;

            const int4 rt = rowtab[(size_t)b * IMG_H + y];
            const int r0 = rt.x;
            const int r1 = rt.y;
            const float wr = __int_as_float(rt.z);
            const float omwr = 1.0f - wr;
            const float* p = images + ((size_t)b * NCH + ch) * (IMG_H * IMG_W);
            const int4* ctb = coltab + (size_t)b * IMG_W;
            const float4 base = ((const float4*)images)[gbase + c];
            float4 res;
            #pragma unroll
            for (int j = 0; j < 4; ++j) {
                const int x = xq * 4 + j;
                const int4 cc = ctb[x];
                const int c0 = cc.x;
                const int c1 = cc.y;
                const float wc = __int_as_float(cc.z);
                const float omwc = 1.0f - wc;
                const float v00 = p[r0 * IMG_W + c0];
                const float v10 = p[r1 * IMG_W + c0];
                const float v01 = p[r0 * IMG_W + c1];
                const float v11 = p[r1 * IMG_W + c1];
                const float rb0 = v00 * omwr + v10 * wr;
                const float rb1 = v01 * omwr + v11 * wr;
                const float patch = rb0 * omwc + rb1 * wc;
                (&res.x)[j] = (&base.x)[j] * 0.6f + patch * 0.4f;
            }
            ((float4*)out)[gbase + c] = res;
        }
    }
}

extern "C" void kernel_launch(void* const* d_in, const int* in_sizes, int n_in,
                              void* d_out, int out_size, void* d_ws, size_t ws_size,
                              hipStream_t stream) {
    const float* images = (const float*)d_in[0];
    const float* atten  = (const float*)d_in[1];
    float* out = (float*)d_out;
    // workspace layout:
    //   [0, 16384)            strip_box: 32 * 32 * 4 ints
    //   [16384, 262144)       rowtab: 32 * 480 int4 (w = full-crop flag)
    //   [262144, 507904)      coltab: 32 * 480 int4
    int* strip_box = (int*)d_ws;
    int4* rowtab = (int4*)((char*)d_ws + 16384);
    int4* coltab = (int4*)((char*)d_ws + 16384 + 32 * IMG_H * (int)sizeof(int4));

    dim3 mgrid(STRIPS, NB);
    mask_kernel<<<mgrid, 256, 0, stream>>>(atten, strip_box);

    prep_kernel<<<dim3(NB), 512, 0, stream>>>(strip_box, rowtab, coltab);

    dim3 bgrid(GRIDX, NB);
    blend_kernel<<<bgrid, 256, 0, stream>>>(images, rowtab, coltab, out);
}

// Round 8
// 184.715 us; speedup vs baseline: 1.0014x; 1.0014x over previous
//
#include <hip/hip_runtime.h>

#define IMG_H 480
#define IMG_W 480
#define ATT_H 30
#define ATT_W 30
#define ATT_N (ATT_H * ATT_W)
#define PAD 48
#define NCH 3
#define NB 32
#define STRIPS 32           // 480 rows / 15 rows per strip
#define ROWS_PER_STRIP 15

#define FP4_PER_ROW (IMG_W / 4)              // 120
#define FP4_PER_CH  (IMG_H * FP4_PER_ROW)    // 57600
#define FP4_PER_IMG (NCH * FP4_PER_CH)       // 172800 = 256 * 675
#define BLOCKS_PER_IMG 45                    // 45 * 32 = 1440 blocks (<8/CU: all resident)
#define K_ITERS 15                           // 45 * 15 * 256 = 172800 exactly
#define CHUNKS_PER_BLOCK (256 * K_ITERS)     // 3840

// native 16B vector type — __builtin_nontemporal_store requires a scalar /
// ext_vector_type pointee (HIP_vector_type float4 is rejected by clang)
typedef float f32x4 __attribute__((ext_vector_type(4)));

// Kernel 1: per-strip mask bbox. Each block computes theta (0.5*max) itself
// (deterministic, identical across blocks) and writes its strip's raw bbox to
// a private slot — no global atomics, no init dependency on ws contents.
__global__ void __launch_bounds__(256) mask_kernel(const float* __restrict__ atten,
                                                   int* __restrict__ strip_box) {
    const int strip = blockIdx.x;
    const int b = blockIdx.y;
    const int tid = threadIdx.x;
    __shared__ float s_att[ATT_N];
    __shared__ float s_red[4];
    __shared__ int s_box[4];   // minr, maxr, minc, maxc

    const float* a = atten + (size_t)b * ATT_N;
    for (int i = tid; i < ATT_N; i += 256) s_att[i] = a[i];
    if (tid == 0) { s_box[0] = IMG_H; s_box[1] = -1; s_box[2] = IMG_W; s_box[3] = -1; }
    __syncthreads();

    // block max over the 900 attention values (order-independent => exact)
    float m = -1e30f;
    for (int i = tid; i < ATT_N; i += 256) m = fmaxf(m, s_att[i]);
    #pragma unroll
    for (int off = 32; off > 0; off >>= 1) m = fmaxf(m, __shfl_down(m, off, 64));
    if ((tid & 63) == 0) s_red[tid >> 6] = m;
    __syncthreads();
    const float theta = 0.5f * fmaxf(fmaxf(s_red[0], s_red[1]), fmaxf(s_red[2], s_red[3]));

    const int y_base = strip * ROWS_PER_STRIP;
    int minr = IMG_H, maxr = -1, minc = IMG_W, maxc = -1;
    for (int p = tid; p < ROWS_PER_STRIP * IMG_W; p += 256) {
        const int yy = p / IMG_W;
        const int y = y_base + yy;
        const int x = p - yy * IMG_W;
        // source coords: (i+0.5)*(30/480) - 0.5, clipped — scale is exactly 1/16
        float sy = (y + 0.5f) * 0.0625f - 0.5f;
        sy = fminf(fmaxf(sy, 0.0f), (float)(ATT_H - 1));
        const float fy0 = floorf(sy);
        const int r0 = (int)fy0;
        const int r1 = min(r0 + 1, ATT_H - 1);
        const float wr = sy - fy0;

        float sx = (x + 0.5f) * 0.0625f - 0.5f;
        sx = fminf(fmaxf(sx, 0.0f), (float)(ATT_W - 1));
        const float fx0 = floorf(sx);
        const int c0 = (int)fx0;
        const int c1 = min(c0 + 1, ATT_W - 1);
        const float wc = sx - fx0;

        // same op order as reference: row blend first, then column blend
        const float rb0 = s_att[r0 * ATT_W + c0] * (1.0f - wr) + s_att[r1 * ATT_W + c0] * wr;
        const float rb1 = s_att[r0 * ATT_W + c1] * (1.0f - wr) + s_att[r1 * ATT_W + c1] * wr;
        const float v = rb0 * (1.0f - wc) + rb1 * wc;
        if (v >= theta) {
            minr = min(minr, y); maxr = max(maxr, y);
            minc = min(minc, x); maxc = max(maxc, x);
        }
    }
    atomicMin(&s_box[0], minr); atomicMax(&s_box[1], maxr);
    atomicMin(&s_box[2], minc); atomicMax(&s_box[3], maxc);
    __syncthreads();
    if (tid == 0) {
        int* dst = strip_box + ((size_t)b * STRIPS + strip) * 4;
        dst[0] = s_box[0]; dst[1] = s_box[1]; dst[2] = s_box[2]; dst[3] = s_box[3];
    }
}

// Kernel 1.5: per-image prep. Reduce strip bboxes, precompute bilinear tables
// (bit-exact same expressions), and detect the DEGENERATE full-crop case:
// h0==0 && h1==H && w0==0 && w1==W  =>  scale==1 exactly => sy==y, sx==x,
// wr==wc==0 => the reference's patch equals base BITWISE (all other taps have
// exact 0.0 weights; only -0.0 -> +0.0 can differ, absdiff 0). Flag goes in
// rowtab[.].w so blend needs no extra load.
__global__ void __launch_bounds__(512) prep_kernel(const int* __restrict__ strip_box,
                                                   int4* __restrict__ rowtab,
                                                   int4* __restrict__ coltab) {
    const int b = blockIdx.x;
    const int tid = threadIdx.x;

    int minr = IMG_H, maxr = -1, minc = IMG_W, maxc = -1;
    const int* sb = strip_box + (size_t)b * STRIPS * 4;
    #pragma unroll
    for (int s = 0; s < STRIPS; ++s) {
        minr = min(minr, sb[s * 4 + 0]); maxr = max(maxr, sb[s * 4 + 1]);
        minc = min(minc, sb[s * 4 + 2]); maxc = max(maxc, sb[s * 4 + 3]);
    }
    const int h0 = max(minr - PAD, 0);
    const int h1 = min(maxr + PAD, IMG_H);
    const int w0 = max(minc - PAD, 0);
    const int w1 = min(maxc + PAD, IMG_W);
    const float cropH = (float)(h1 - h0);
    const float cropW = (float)(w1 - w0);
    const int full = (h0 == 0 && h1 == IMG_H && w0 == 0 && w1 == IMG_W) ? 1 : 0;

    if (tid < IMG_H) {
        // row entry (reference op order, identical expressions to old blend)
        float sy = (tid + 0.5f) * (cropH / (float)IMG_H) - 0.5f;
        sy = fminf(fmaxf(sy, 0.0f), cropH - 1.0f);
        const float fy0 = floorf(sy);
        const float fy1 = fminf(fy0 + 1.0f, cropH - 1.0f);
        const float wr = sy - fy0;
        rowtab[(size_t)b * IMG_H + tid] =
            make_int4(h0 + (int)fy0, h0 + (int)fy1, __float_as_int(wr), full);

        // col entry
        float sx = (tid + 0.5f) * (cropW / (float)IMG_W) - 0.5f;
        sx = fminf(fmaxf(sx, 0.0f), cropW - 1.0f);
        const float fx0 = floorf(sx);
        const float fx1 = fminf(fx0 + 1.0f, cropW - 1.0f);
        const float wc = sx - fx0;
        coltab[(size_t)b * IMG_W + tid] =
            make_int4(w0 + (int)fx0, w0 + (int)fx1, __float_as_int(wc), 0);
    }
}

// Kernel 2 — ROUND 8 (= round 7 with the nt-store type fixed): persistent grid
// + nontemporal stores.
//  (1) WRITE_SIZE=86MB of stores write-ALLOCATE in L2/L3, evicting half the
//      88MB input (FETCH=43MB shows the other half survives replays). The
//      never-re-read out stream shouldn't touch caches: nt stores.
//  (2) 4320 short-lived blocks (~17 sequential per CU), each paying a serial
//      kernarg->flag load chain before moving a byte (Occupancy ~50% ramp
//      signature). 1440 blocks (<8/CU) are ALL resident at once: zero churn,
//      15 fully-unrolled independent float4 pairs per thread (240B/lane MLP).
// nt store changes cache policy only, not values; general path keeps the
// exact per-chunk expressions => bit-exact, data-independent correctness.
__global__ void __launch_bounds__(256) blend_kernel(const float* __restrict__ images,
                                                    const int4* __restrict__ rowtab,
                                                    const int4* __restrict__ coltab,
                                                    float* __restrict__ out) {
    const int b = blockIdx.y;
    const int tid = threadIdx.x;
    const int cbase = blockIdx.x * CHUNKS_PER_BLOCK + tid;  // chunk index in image
    const size_t gbase = (size_t)b * FP4_PER_IMG;
    const int full = rowtab[(size_t)b * IMG_H].w;           // uniform => scalar branch

    if (full) {
        const f32x4* src = (const f32x4*)images + gbase;
        f32x4* dst = (f32x4*)out + gbase;
        #pragma unroll
        for (int u = 0; u < K_ITERS; ++u) {
            const int c = cbase + u * 256;
            const f32x4 v = src[c];
            f32x4 r;
            r.x = v.x * 0.6f + v.x * 0.4f;
            r.y = v.y * 0.6f + v.y * 0.4f;
            r.z = v.z * 0.6f + v.z * 0.4f;
            r.w = v.w * 0.6f + v.w * 0.4f;
            __builtin_nontemporal_store(r, &dst[c]);
        }
    } else {
        // general path — exact round-5/6 expressions
        #pragma unroll
        for (int u = 0; u < K_ITERS; ++u) {
            const int c = cbase + u * 256;
            const int ch   = c / FP4_PER_CH;
            const int rem2 = c - ch * FP4_PER_CH;
            const int y    = rem2 / FP4_PER_ROW;
            const int xq   = rem2 - y * FP4_PER_ROW;

            const int4 rt = rowtab[(size_t)b * IMG_H + y];
            const int r0 = rt.x;
            const int r1 = rt.y;
            const float wr = __int_as_float(rt.z);
            const float omwr = 1.0f - wr;
            const float* p = images + ((size_t)b * NCH + ch) * (IMG_H * IMG_W);
            const int4* ctb = coltab + (size_t)b * IMG_W;
            const f32x4 base = ((const f32x4*)images)[gbase + c];
            f32x4 res;
            #pragma unroll
            for (int j = 0; j < 4; ++j) {
                const int x = xq * 4 + j;
                const int4 cc = ctb[x];
                const int c0 = cc.x;
                const int c1 = cc.y;
                const float wc = __int_as_float(cc.z);
                const float omwc = 1.0f - wc;
                const float v00 = p[r0 * IMG_W + c0];
                const float v10 = p[r1 * IMG_W + c0];
                const float v01 = p[r0 * IMG_W + c1];
                const float v11 = p[r1 * IMG_W + c1];
                const float rb0 = v00 * omwr + v10 * wr;
                const float rb1 = v01 * omwr + v11 * wr;
                const float patch = rb0 * omwc + rb1 * wc;
                res[j] = base[j] * 0.6f + patch * 0.4f;
            }
            __builtin_nontemporal_store(res, &((f32x4*)out)[gbase + c]);
        }
    }
}

extern "C" void kernel_launch(void* const* d_in, const int* in_sizes, int n_in,
                              void* d_out, int out_size, void* d_ws, size_t ws_size,
                              hipStream_t stream) {
    const float* images = (const float*)d_in[0];
    const float* atten  = (const float*)d_in[1];
    float* out = (float*)d_out;
    // workspace layout:
    //   [0, 16384)            strip_box: 32 * 32 * 4 ints
    //   [16384, 262144)       rowtab: 32 * 480 int4 (w = full-crop flag)
    //   [262144, 507904)      coltab: 32 * 480 int4
    int* strip_box = (int*)d_ws;
    int4* rowtab = (int4*)((char*)d_ws + 16384);
    int4* coltab = (int4*)((char*)d_ws + 16384 + 32 * IMG_H * (int)sizeof(int4));

    dim3 mgrid(STRIPS, NB);
    mask_kernel<<<mgrid, 256, 0, stream>>>(atten, strip_box);

    prep_kernel<<<dim3(NB), 512, 0, stream>>>(strip_box, rowtab, coltab);

    dim3 bgrid(BLOCKS_PER_IMG, NB);
    blend_kernel<<<bgrid, 256, 0, stream>>>(images, rowtab, coltab, out);
}